// Round 1
// baseline (768.328 us; speedup 1.0000x reference)
//
#include <hip/hip_runtime.h>
#include <stdint.h>

#define NB 16
#define NN 4096
#define KK 10
#define FD 64
#define TOTAL (NB * NN)

// ---------------------------------------------------------------------------
// Kernel 1: brute-force kNN per batch.
// One thread per query node; whole batch's positions staged in LDS as
// float4(x,y,z,sq). Top-10 kept as sorted (descending, L[0]=worst) uint64
// keys = (d2_bits<<32)|local_idx  -> exact lexicographic (d2, idx) order,
// matching lax.top_k tie semantics.
// Distance formula replicates numpy bit pattern: no FMA contraction.
// ---------------------------------------------------------------------------
__global__ __launch_bounds__(256) void knn_kernel(const float* __restrict__ pos,
                                                  int* __restrict__ nbr,
                                                  int* __restrict__ cnt) {
    __shared__ float4 tile[NN];  // 64 KB
    const int tid = threadIdx.x;
    const int blocks_per_batch = NN / 256;          // 16
    const int batch = blockIdx.x / blocks_per_batch;
    const int qbase = (blockIdx.x % blocks_per_batch) * 256;

    const float* pb = pos + (size_t)batch * NN * 3;
    for (int idx = tid; idx < NN; idx += 256) {
        float px = pb[idx * 3 + 0];
        float py = pb[idx * 3 + 1];
        float pz = pb[idx * 3 + 2];
        float sq = __fadd_rn(__fadd_rn(__fmul_rn(px, px), __fmul_rn(py, py)),
                             __fmul_rn(pz, pz));
        tile[idx] = make_float4(px, py, pz, sq);
    }
    __syncthreads();

    const int q = qbase + tid;            // local query index
    const float4 me = tile[q];
    const float px = me.x, py = me.y, pz = me.z, sqi = me.w;

    uint64_t L[KK];
#pragma unroll
    for (int t = 0; t < KK; t++) L[t] = ~0ull;

#pragma unroll 4
    for (int j = 0; j < NN; j++) {
        float4 c = tile[j];
        float dot = __fadd_rn(__fadd_rn(__fmul_rn(px, c.x), __fmul_rn(py, c.y)),
                              __fmul_rn(pz, c.z));
        float d2 = __fsub_rn(__fadd_rn(sqi, c.w), __fmul_rn(2.0f, dot));
        uint64_t key = ((uint64_t)__float_as_uint(d2) << 32) | (uint32_t)j;
        if (j != q && key < L[0]) {
            // branchless sorted insert (fully unrolled, register-resident)
            bool sh[KK];
            sh[0] = true;
#pragma unroll
            for (int t = 1; t < KK; t++) sh[t] = (key < L[t]);
#pragma unroll
            for (int t = 0; t < KK; t++) {
                uint64_t vac = sh[t] ? key : L[t];
                L[t] = (t + 1 < KK) ? (sh[t + 1] ? L[t + 1] : vac) : vac;
            }
        }
    }

    const int gq = batch * NN + q;
#pragma unroll
    for (int t = 0; t < KK; t++) {
        int jl = (int)(L[t] & 0xffffffffu);
        int gj = batch * NN + jl;
        nbr[gq * KK + t] = gj;
        atomicAdd(&cnt[gj], 1);
    }
}

// ---------------------------------------------------------------------------
// Kernel 2: exclusive prefix scan of cnt[TOTAL] -> offs[TOTAL].
// Single block, 1024 threads, 64 elements each; Hillis-Steele over partials.
// ---------------------------------------------------------------------------
__global__ __launch_bounds__(1024) void scan_kernel(const int* __restrict__ cnt,
                                                    int* __restrict__ offs) {
    __shared__ int lds[1024];
    const int t = threadIdx.x;
    const int base = t * 64;
    int s = 0;
    for (int i = 0; i < 64; i++) s += cnt[base + i];
    lds[t] = s;
    __syncthreads();
    for (int off = 1; off < 1024; off <<= 1) {
        int v = (t >= off) ? lds[t - off] : 0;
        __syncthreads();
        lds[t] += v;
        __syncthreads();
    }
    int run = lds[t] - s;  // exclusive prefix of this chunk
    for (int i = 0; i < 64; i++) {
        offs[base + i] = run;
        run += cnt[base + i];
    }
}

// ---------------------------------------------------------------------------
// Kernel 3: fill CSR col array. offs used as atomic cursors; afterwards
// offs[j] == end offset of segment j (start recoverable via cnt[j]).
// ---------------------------------------------------------------------------
__global__ __launch_bounds__(256) void fill_kernel(const int* __restrict__ nbr,
                                                   int* __restrict__ offs,
                                                   int* __restrict__ col) {
    const int i = blockIdx.x * 256 + threadIdx.x;  // query node (global)
#pragma unroll
    for (int t = 0; t < KK; t++) {
        int j = nbr[i * KK + t];
        int p = atomicAdd(&offs[j], 1);
        col[p] = i;
    }
}

// ---------------------------------------------------------------------------
// Kernel 4: one wave per node; lane = feature dim. Gather x rows of queries
// that selected this node, mean, L1 vs own features, wave-reduce, store.
// ---------------------------------------------------------------------------
__global__ __launch_bounds__(256) void out_kernel(const float* __restrict__ x,
                                                  const int* __restrict__ col,
                                                  const int* __restrict__ offs_end,
                                                  const int* __restrict__ cnt,
                                                  float* __restrict__ out) {
    const int gtid = blockIdx.x * 256 + threadIdx.x;
    const int n = gtid >> 6;       // node
    const int lane = gtid & 63;    // feature dim
    const int c = cnt[n];
    const int end = offs_end[n];
    const int start = end - c;
    float s = 0.0f;
    for (int e = start; e < end; e++) {
        int i = col[e];
        s += x[(size_t)i * FD + lane];
    }
    float mean = s / (float)(c > 1 ? c : 1);
    float v = fabsf(x[(size_t)n * FD + lane] - mean);
#pragma unroll
    for (int off = 32; off; off >>= 1) v += __shfl_xor(v, off, 64);
    if (lane == 0) out[n] = v;
}

extern "C" void kernel_launch(void* const* d_in, const int* in_sizes, int n_in,
                              void* d_out, int out_size, void* d_ws, size_t ws_size,
                              hipStream_t stream) {
    const float* x = (const float*)d_in[0];
    const float* pos = (const float*)d_in[1];
    float* out = (float*)d_out;

    // workspace layout (all 256B-aligned)
    char* ws = (char*)d_ws;
    int* nbr = (int*)(ws + 0);                    // TOTAL*KK ints  = 2,621,440 B
    int* cnt = (int*)(ws + 2621440);              // TOTAL ints     =   262,144 B
    int* offs = (int*)(ws + 2883584);             // TOTAL ints     =   262,144 B
    int* col = (int*)(ws + 3145728);              // TOTAL*KK ints  = 2,621,440 B

    hipMemsetAsync(cnt, 0, TOTAL * sizeof(int), stream);
    hipLaunchKernelGGL(knn_kernel, dim3(TOTAL / 256), dim3(256), 0, stream, pos, nbr, cnt);
    hipLaunchKernelGGL(scan_kernel, dim3(1), dim3(1024), 0, stream, cnt, offs);
    hipLaunchKernelGGL(fill_kernel, dim3(TOTAL / 256), dim3(256), 0, stream, nbr, offs, col);
    hipLaunchKernelGGL(out_kernel, dim3(TOTAL * FD / 256), dim3(256), 0, stream, x, col, offs, cnt, out);
}

// Round 2
// 445.769 us; speedup vs baseline: 1.7236x; 1.7236x over previous
//
#include <hip/hip_runtime.h>
#include <stdint.h>

#define NB 16
#define NN 4096
#define KK 10
#define FD 64
#define TOTAL (NB * NN)
#define CH 1024     // candidates per chunk (per wave)
#define NW 4        // chunks/waves per query group
#define QG 64       // queries per block (one per lane)
#define SPITCH 33   // stack pitch in u32 words (odd -> no bank clustering)
#define SCAP 16     // stack capacity in (d2,idx) entries

// v_med3_u32 via inline asm (no reliable HIP builtin for integer med3)
__device__ __forceinline__ uint32_t med3u(uint32_t a, uint32_t b, uint32_t c) {
    uint32_t d;
    asm("v_med3_u32 %0, %1, %2, %3" : "=v"(d) : "v"(a), "v"(b), "v"(c));
    return d;
}

// EXACT same rounding as the round-1-passing kernel: no FMA contraction.
__device__ __forceinline__ uint32_t dist2u(float4 me, float4 c) {
    float dot = __fadd_rn(__fadd_rn(__fmul_rn(me.x, c.x), __fmul_rn(me.y, c.y)),
                          __fmul_rn(me.z, c.z));
    float d2 = __fsub_rn(__fadd_rn(me.w, c.w), __fmul_rn(2.0f, dot));
    return __float_as_uint(d2);
}

// ---------------------------------------------------------------------------
// Prep: pack pos -> float4(x,y,z,|p|^2), numpy rounding for sq.
// ---------------------------------------------------------------------------
__global__ __launch_bounds__(256) void prep_kernel(const float* __restrict__ pos,
                                                   float4* __restrict__ pf4) {
    const int i = blockIdx.x * 256 + threadIdx.x;
    float px = pos[3 * i + 0], py = pos[3 * i + 1], pz = pos[3 * i + 2];
    float sq = __fadd_rn(__fadd_rn(__fmul_rn(px, px), __fmul_rn(py, py)),
                         __fmul_rn(pz, pz));
    pf4[i] = make_float4(px, py, pz, sq);
}

// ---------------------------------------------------------------------------
// kNN: block = 256 threads = 4 waves; 64 queries (lane = query), wave = 1024-
// candidate chunk. Pass1: branchless med3 threshold list (values only).
// Merge: exact 10th-smallest across 4 chunks -> tau. Pass2: replay, collect
// survivors (d2<=tau) into LDS stacks. Select: exact (d2,idx) top-10.
// ---------------------------------------------------------------------------
__global__ __launch_bounds__(256) void knn_kernel(const float4* __restrict__ pf4,
                                                  int* __restrict__ nbr,
                                                  int* __restrict__ cnt) {
    // layout: [0, 256*SPITCH) stacks (aliased with pass1 vlist at [0,2560)),
    //         [256*SPITCH, +QG) tau, [+QG, +QG+256) per-thread survivor counts
    __shared__ uint32_t sm[256 * SPITCH + QG + 256];

    const int tid = threadIdx.x;
    const int lane = tid & 63;
    const int w = __builtin_amdgcn_readfirstlane(tid >> 6);
    const int batch = blockIdx.x >> 6;                 // 64 blocks per batch
    const int qloc = ((blockIdx.x & 63) << 6) | lane;  // local query idx
    const int gbase = batch << 12;
    const float4 me = pf4[gbase + qloc];
    const float4* __restrict__ cb = pf4 + gbase + (w << 10);
    const int selfj = qloc - (w << 10);                // chunk-local self idx

    // ---- pass 1: threshold list (10 smallest d2 values), descending L[0]=max
    uint32_t L[KK];
#pragma unroll
    for (int t = 0; t < KK; t++) L[t] = ~0u;

#pragma unroll 4
    for (int j = 0; j < CH; ++j) {
        float4 c = cb[j];
        uint32_t key = dist2u(me, c);
        key = (j == selfj) ? ~0u : key;
#pragma unroll
        for (int t = 0; t < KK - 1; ++t) L[t] = med3u(L[t], L[t + 1], key);
        L[KK - 1] = (L[KK - 1] < key) ? L[KK - 1] : key;
    }

    // write value lists (pitch KK) into the (currently unused) stack region
#pragma unroll
    for (int t = 0; t < KK; t++) sm[tid * KK + t] = L[t];
    __syncthreads();

    // ---- merge: exact 10th-smallest of the 4-list union, per query
    if (tid < QG) {
        int p[NW];
#pragma unroll
        for (int u = 0; u < NW; u++) p[u] = KK - 1;  // lists descending; tail = min
        uint32_t tau = ~0u;
        for (int it = 0; it < KK; ++it) {
            uint32_t best = ~0u;
            int bw = 0;
#pragma unroll
            for (int u = 0; u < NW; u++) {
                uint32_t v = (p[u] >= 0) ? sm[(u * QG + tid) * KK + p[u]] : ~0u;
                if (v < best) { best = v; bw = u; }
            }
            p[bw]--;
            tau = best;
        }
        sm[256 * SPITCH + tid] = tau;
    }
    __syncthreads();

    // ---- pass 2: replay, collect survivors (d2 <= tau, not self)
    const uint32_t tau = sm[256 * SPITCH + lane];
    uint32_t* st = &sm[tid * SPITCH];
    uint32_t scnt = 0;
#pragma unroll 4
    for (int j = 0; j < CH; ++j) {
        float4 c = cb[j];
        uint32_t key = dist2u(me, c);
        if (key <= tau && j != selfj) {
            if (scnt < SCAP) {
                st[2 * scnt + 0] = key;
                st[2 * scnt + 1] = (uint32_t)j;
                scnt++;
            }
        }
    }
    sm[256 * SPITCH + QG + tid] = scnt;
    __syncthreads();

    // ---- select: exact (d2, idx) top-10 over ~10 survivors, write edges
    if (tid < QG) {
        uint64_t S[KK];
#pragma unroll
        for (int t = 0; t < KK; t++) S[t] = ~0ull;
#pragma unroll
        for (int u = 0; u < NW; u++) {
            uint32_t c2 = sm[256 * SPITCH + QG + u * QG + tid];
            const uint32_t* st2 = &sm[(u * QG + tid) * SPITCH];
            for (uint32_t e = 0; e < c2; ++e) {
                uint64_t k64 = ((uint64_t)st2[2 * e] << 32) |
                               (uint32_t)((u << 10) + st2[2 * e + 1]);
                if (k64 < S[0]) {
                    bool sh[KK];
                    sh[0] = true;
#pragma unroll
                    for (int t = 1; t < KK; t++) sh[t] = (k64 < S[t]);
#pragma unroll
                    for (int t = 0; t < KK; t++) {
                        uint64_t vac = sh[t] ? k64 : S[t];
                        S[t] = (t + 1 < KK) ? (sh[t + 1] ? S[t + 1] : vac) : vac;
                    }
                }
            }
        }
        const int gq = gbase + qloc;  // lane==tid here
#pragma unroll
        for (int t = 0; t < KK; t++) {
            int jl = (int)(S[t] & 0xffffffffu);
            int gj = gbase + jl;
            nbr[gq * KK + t] = gj;
            atomicAdd(&cnt[gj], 1);
        }
    }
}

// ---------------------------------------------------------------------------
// Exclusive prefix scan of cnt[TOTAL] -> offs[TOTAL]. Single block.
// ---------------------------------------------------------------------------
__global__ __launch_bounds__(1024) void scan_kernel(const int* __restrict__ cnt,
                                                    int* __restrict__ offs) {
    __shared__ int lds[1024];
    const int t = threadIdx.x;
    const int base = t * 64;
    int s = 0;
    for (int i = 0; i < 64; i++) s += cnt[base + i];
    lds[t] = s;
    __syncthreads();
    for (int off = 1; off < 1024; off <<= 1) {
        int v = (t >= off) ? lds[t - off] : 0;
        __syncthreads();
        lds[t] += v;
        __syncthreads();
    }
    int run = lds[t] - s;
    for (int i = 0; i < 64; i++) {
        offs[base + i] = run;
        run += cnt[base + i];
    }
}

// ---------------------------------------------------------------------------
// Fill CSR col array; offs becomes end-offsets.
// ---------------------------------------------------------------------------
__global__ __launch_bounds__(256) void fill_kernel(const int* __restrict__ nbr,
                                                   int* __restrict__ offs,
                                                   int* __restrict__ col) {
    const int i = blockIdx.x * 256 + threadIdx.x;
#pragma unroll
    for (int t = 0; t < KK; t++) {
        int j = nbr[i * KK + t];
        int p = atomicAdd(&offs[j], 1);
        col[p] = i;
    }
}

// ---------------------------------------------------------------------------
// Output: one wave per node, lane = feature dim; gather, mean, L1, reduce.
// ---------------------------------------------------------------------------
__global__ __launch_bounds__(256) void out_kernel(const float* __restrict__ x,
                                                  const int* __restrict__ col,
                                                  const int* __restrict__ offs_end,
                                                  const int* __restrict__ cnt,
                                                  float* __restrict__ out) {
    const int gtid = blockIdx.x * 256 + threadIdx.x;
    const int n = gtid >> 6;
    const int lane = gtid & 63;
    const int c = cnt[n];
    const int end = offs_end[n];
    const int start = end - c;
    float s = 0.0f;
    for (int e = start; e < end; e++) {
        int i = col[e];
        s += x[(size_t)i * FD + lane];
    }
    float mean = s / (float)(c > 1 ? c : 1);
    float v = fabsf(x[(size_t)n * FD + lane] - mean);
#pragma unroll
    for (int off = 32; off; off >>= 1) v += __shfl_xor(v, off, 64);
    if (lane == 0) out[n] = v;
}

extern "C" void kernel_launch(void* const* d_in, const int* in_sizes, int n_in,
                              void* d_out, int out_size, void* d_ws, size_t ws_size,
                              hipStream_t stream) {
    const float* x = (const float*)d_in[0];
    const float* pos = (const float*)d_in[1];
    float* out = (float*)d_out;

    char* ws = (char*)d_ws;
    int* nbr = (int*)(ws + 0);                 // TOTAL*KK ints  = 2,621,440 B
    int* cnt = (int*)(ws + 2621440);           // TOTAL ints     =   262,144 B
    int* offs = (int*)(ws + 2883584);          // TOTAL ints     =   262,144 B
    int* col = (int*)(ws + 3145728);           // TOTAL*KK ints  = 2,621,440 B
    float4* pf4 = (float4*)(ws + 5767168);     // TOTAL float4   = 1,048,576 B

    hipMemsetAsync(cnt, 0, TOTAL * sizeof(int), stream);
    hipLaunchKernelGGL(prep_kernel, dim3(TOTAL / 256), dim3(256), 0, stream, pos, pf4);
    hipLaunchKernelGGL(knn_kernel, dim3(TOTAL / QG), dim3(256), 0, stream, pf4, nbr, cnt);
    hipLaunchKernelGGL(scan_kernel, dim3(1), dim3(1024), 0, stream, cnt, offs);
    hipLaunchKernelGGL(fill_kernel, dim3(TOTAL / 256), dim3(256), 0, stream, nbr, offs, col);
    hipLaunchKernelGGL(out_kernel, dim3(TOTAL * FD / 256), dim3(256), 0, stream, x, col, offs, cnt, out);
}

// Round 3
// 266.695 us; speedup vs baseline: 2.8809x; 1.6715x over previous
//
#include <hip/hip_runtime.h>
#include <stdint.h>

#define NB 16
#define NN 4096
#define KK 10
#define FD 64
#define TOTAL (NB * NN)
#define NW 8        // waves per knn block
#define CH 512      // candidates per wave chunk (NW*CH == NN)
#define SAMP 256    // pass1 sample per chunk (half) -> tau from 2048-subset
#define QG 64       // queries per block (one per lane)
#define PCAP 64     // survivor pool cap per query (mean ~20, ~10 sigma margin)
#define PPITCH 129  // pool pitch in words per query (odd*? -> bank-conflict-free)

__device__ __forceinline__ uint32_t med3u(uint32_t a, uint32_t b, uint32_t c) {
    uint32_t d;
    asm("v_med3_u32 %0, %1, %2, %3" : "=v"(d) : "v"(a), "v"(b), "v"(c));
    return d;
}

// EXACT numpy rounding: no FMA contraction. DO NOT CHANGE (absmax-stable at 0.75).
__device__ __forceinline__ uint32_t dist2u(float4 me, float4 c) {
    float dot = __fadd_rn(__fadd_rn(__fmul_rn(me.x, c.x), __fmul_rn(me.y, c.y)),
                          __fmul_rn(me.z, c.z));
    float d2 = __fsub_rn(__fadd_rn(me.w, c.w), __fmul_rn(2.0f, dot));
    return __float_as_uint(d2);
}

__global__ __launch_bounds__(256) void prep_kernel(const float* __restrict__ pos,
                                                   float4* __restrict__ pf4) {
    const int i = blockIdx.x * 256 + threadIdx.x;
    float px = pos[3 * i + 0], py = pos[3 * i + 1], pz = pos[3 * i + 2];
    float sq = __fadd_rn(__fadd_rn(__fmul_rn(px, px), __fmul_rn(py, py)),
                         __fmul_rn(pz, pz));
    pf4[i] = make_float4(px, py, pz, sq);
}

// ---------------------------------------------------------------------------
// kNN: block = 512 thr = 8 waves; 64 queries (lane = query), wave = 512-cand
// chunk. Pass1: exact med3 top-10 over first 256 of chunk -> LDS lists.
// Merge: 10th smallest of 8x10 union = conservative tau (subset order-stat
// >= global 10th). Pass2: full-chunk replay, push survivors (d2<=tau) into
// per-query LDS pools. Select: exact (d2,idx) top-10, write edges.
// Bucket path: colfix[j*64 + p] = q directly (no scan/fill). Fallback: nbr.
// ---------------------------------------------------------------------------
__global__ __launch_bounds__(512, 8) void knn_kernel(const float4* __restrict__ pf4,
                                                     int* __restrict__ cnt,
                                                     int* __restrict__ colfix,
                                                     int* __restrict__ nbr) {
    __shared__ uint32_t pool[QG * PPITCH];  // 33 KB; pass1 lists alias first 5120 words
    __shared__ uint32_t tau_s[QG];
    __shared__ unsigned int qcnt[QG];

    const int tid = threadIdx.x;
    const int lane = tid & 63;
    const int w = __builtin_amdgcn_readfirstlane(tid >> 6);
    const int batch = blockIdx.x >> 6;
    const int qloc = ((blockIdx.x & 63) << 6) | lane;
    const int gbase = batch << 12;
    const float4 me = pf4[gbase + qloc];
    const float4* __restrict__ cb = pf4 + gbase + w * CH;
    const int selfj = qloc - w * CH;  // in [0,CH) only for the self-owning wave

    // ---- pass 1: exact top-10 values over first SAMP candidates of chunk
    uint32_t L[KK];
#pragma unroll
    for (int t = 0; t < KK; t++) L[t] = ~0u;
#pragma unroll 4
    for (int j = 0; j < SAMP; ++j) {
        float4 c = cb[j];
        uint32_t key = dist2u(me, c);
        key = (j == selfj) ? ~0u : key;
#pragma unroll
        for (int t = 0; t < KK - 1; ++t) L[t] = med3u(L[t], L[t + 1], key);
        L[KK - 1] = (L[KK - 1] < key) ? L[KK - 1] : key;
    }
#pragma unroll
    for (int t = 0; t < KK; t++) pool[tid * KK + t] = L[t];
    if (tid < QG) qcnt[tid] = 0u;
    __syncthreads();

    // ---- merge: 10th smallest of the 8-list union -> tau (conservative)
    if (tid < QG) {
        int p[NW];
#pragma unroll
        for (int u = 0; u < NW; u++) p[u] = KK - 1;  // lists descending; tail = min
        uint32_t tau = ~0u;
        for (int it = 0; it < KK; ++it) {
            uint32_t best = ~0u;
            int bw = 0;
#pragma unroll
            for (int u = 0; u < NW; u++) {
                uint32_t v = (p[u] >= 0) ? pool[(u * QG + tid) * KK + p[u]] : ~0u;
                if (v < best) { best = v; bw = u; }
            }
            p[bw]--;
            tau = best;
        }
        tau_s[tid] = tau;
    }
    __syncthreads();

    // ---- pass 2: full-chunk replay, collect survivors into per-query pools
    const uint32_t tau = tau_s[lane];
#pragma unroll 4
    for (int j = 0; j < CH; ++j) {
        float4 c = cb[j];
        uint32_t key = dist2u(me, c);
        if (key <= tau && j != selfj) {
            unsigned int p = atomicAdd(&qcnt[lane], 1u);
            if (p < PCAP) {
                pool[lane * PPITCH + 2 * p + 0] = key;
                pool[lane * PPITCH + 2 * p + 1] = (uint32_t)(w * CH + j);
            }
        }
    }
    __syncthreads();

    // ---- select: exact (d2, idx) top-10 over survivors, write edges
    if (tid < QG) {
        uint64_t S[KK];
#pragma unroll
        for (int t = 0; t < KK; t++) S[t] = ~0ull;
        unsigned int R = qcnt[tid];
        if (R > PCAP) R = PCAP;
        for (unsigned int e = 0; e < R; ++e) {
            uint64_t k64 = ((uint64_t)pool[tid * PPITCH + 2 * e] << 32) |
                           pool[tid * PPITCH + 2 * e + 1];
            if (k64 < S[0]) {
                bool sh[KK];
                sh[0] = true;
#pragma unroll
                for (int t = 1; t < KK; t++) sh[t] = (k64 < S[t]);
#pragma unroll
                for (int t = 0; t < KK; t++) {
                    uint64_t vac = sh[t] ? k64 : S[t];
                    S[t] = (t + 1 < KK) ? (sh[t + 1] ? S[t + 1] : vac) : vac;
                }
            }
        }
        const int gq = gbase + qloc;  // wave 0: lane == tid
#pragma unroll
        for (int t = 0; t < KK; t++) {
            int jl = (int)(S[t] & 0xffffffffu);
            int gj = gbase + jl;
            int p = atomicAdd(&cnt[gj], 1);
            if (colfix) {
                if (p < 64) colfix[(gj << 6) | p] = gq;
            } else {
                nbr[gq * KK + t] = gj;
            }
        }
    }
}

// ---------------------------------------------------------------------------
// Bucket-path output: 4 nodes per wave, 16 lanes x float4 per node.
// ---------------------------------------------------------------------------
__global__ __launch_bounds__(256) void out_bucket_kernel(const float4* __restrict__ x4,
                                                         const int* __restrict__ colfix,
                                                         const int* __restrict__ cnt,
                                                         float* __restrict__ out) {
    const int gid = blockIdx.x * 256 + threadIdx.x;
    const int n = gid >> 4;
    const int s = gid & 15;
    const int c = cnt[n];
    const int cc = (c > 64) ? 64 : c;
    const int base = n << 6;
    float4 acc = make_float4(0.f, 0.f, 0.f, 0.f);
    for (int e = 0; e < cc; ++e) {
        int q = colfix[base + e];
        float4 v = x4[(q << 4) | s];
        acc.x += v.x; acc.y += v.y; acc.z += v.z; acc.w += v.w;
    }
    const float inv = 1.0f / (float)(c > 1 ? c : 1);
    float4 mn = x4[(n << 4) | s];
    float v = fabsf(mn.x - acc.x * inv) + fabsf(mn.y - acc.y * inv) +
              fabsf(mn.z - acc.z * inv) + fabsf(mn.w - acc.w * inv);
    v += __shfl_xor(v, 1, 64);
    v += __shfl_xor(v, 2, 64);
    v += __shfl_xor(v, 4, 64);
    v += __shfl_xor(v, 8, 64);
    if (s == 0) out[n] = v;
}

// ------------------------- fallback path (small ws) -------------------------
__global__ __launch_bounds__(1024) void scan_kernel(const int* __restrict__ cnt,
                                                    int* __restrict__ offs) {
    __shared__ int lds[1024];
    const int t = threadIdx.x;
    const int base = t * 64;
    int s = 0;
    for (int i = 0; i < 64; i++) s += cnt[base + i];
    lds[t] = s;
    __syncthreads();
    for (int off = 1; off < 1024; off <<= 1) {
        int v = (t >= off) ? lds[t - off] : 0;
        __syncthreads();
        lds[t] += v;
        __syncthreads();
    }
    int run = lds[t] - s;
    for (int i = 0; i < 64; i++) {
        offs[base + i] = run;
        run += cnt[base + i];
    }
}

__global__ __launch_bounds__(256) void fill_kernel(const int* __restrict__ nbr,
                                                   int* __restrict__ offs,
                                                   int* __restrict__ col) {
    const int i = blockIdx.x * 256 + threadIdx.x;
#pragma unroll
    for (int t = 0; t < KK; t++) {
        int j = nbr[i * KK + t];
        int p = atomicAdd(&offs[j], 1);
        col[p] = i;
    }
}

__global__ __launch_bounds__(256) void out_kernel(const float* __restrict__ x,
                                                  const int* __restrict__ col,
                                                  const int* __restrict__ offs_end,
                                                  const int* __restrict__ cnt,
                                                  float* __restrict__ out) {
    const int gtid = blockIdx.x * 256 + threadIdx.x;
    const int n = gtid >> 6;
    const int lane = gtid & 63;
    const int c = cnt[n];
    const int end = offs_end[n];
    const int start = end - c;
    float s = 0.0f;
    for (int e = start; e < end; e++) {
        int i = col[e];
        s += x[(size_t)i * FD + lane];
    }
    float mean = s / (float)(c > 1 ? c : 1);
    float v = fabsf(x[(size_t)n * FD + lane] - mean);
#pragma unroll
    for (int off = 32; off; off >>= 1) v += __shfl_xor(v, off, 64);
    if (lane == 0) out[n] = v;
}

extern "C" void kernel_launch(void* const* d_in, const int* in_sizes, int n_in,
                              void* d_out, int out_size, void* d_ws, size_t ws_size,
                              hipStream_t stream) {
    const float* x = (const float*)d_in[0];
    const float* pos = (const float*)d_in[1];
    float* out = (float*)d_out;

    char* ws = (char*)d_ws;
    float4* pf4 = (float4*)(ws + 0);            // 1,048,576 B
    int* cnt = (int*)(ws + 1048576);            //   262,144 B
    // bucket path (needs 18.1 MB):
    int* colfix = (int*)(ws + 1310720);         // TOTAL*64*4 = 16,777,216 B
    // fallback path (needs 6.8 MB):
    int* nbr = (int*)(ws + 1310720);            // 2,621,440 B
    int* offs = (int*)(ws + 3932160);           //   262,144 B
    int* col = (int*)(ws + 4194304);            // 2,621,440 B

    const bool bucket = ws_size >= (size_t)(1310720 + TOTAL * 64 * 4);

    hipMemsetAsync(cnt, 0, TOTAL * sizeof(int), stream);
    hipLaunchKernelGGL(prep_kernel, dim3(TOTAL / 256), dim3(256), 0, stream, pos, pf4);
    hipLaunchKernelGGL(knn_kernel, dim3(TOTAL / QG), dim3(512), 0, stream, pf4, cnt,
                       bucket ? colfix : (int*)nullptr, bucket ? (int*)nullptr : nbr);
    if (bucket) {
        hipLaunchKernelGGL(out_bucket_kernel, dim3(TOTAL * 16 / 256), dim3(256), 0, stream,
                           (const float4*)x, colfix, cnt, out);
    } else {
        hipLaunchKernelGGL(scan_kernel, dim3(1), dim3(1024), 0, stream, cnt, offs);
        hipLaunchKernelGGL(fill_kernel, dim3(TOTAL / 256), dim3(256), 0, stream, nbr, offs, col);
        hipLaunchKernelGGL(out_kernel, dim3(TOTAL * FD / 256), dim3(256), 0, stream,
                           x, col, offs, cnt, out);
    }
}

// Round 4
// 225.334 us; speedup vs baseline: 3.4097x; 1.1836x over previous
//
#include <hip/hip_runtime.h>
#include <stdint.h>

#define NB 16
#define NN 4096
#define KK 10
#define FD 64
#define TOTAL (NB * NN)
#define NW 8        // waves per knn block
#define CH 512      // candidates per wave chunk (NW*CH == NN)
#define QG 64       // queries per block (one per lane)
#define PCAP 48     // survivor pool cap per query (mean ~15, ~8 sigma margin)
#define PPITCH 97   // pool pitch in words per query (97%32==1 -> conflict-free)

typedef float f2 __attribute__((ext_vector_type(2)));

#define INFF __int_as_float(0x7f800000)

// Packed-pair distance, EXACT reference rounding (mul/add only, contract off):
// nm = -m (exact); dot' = (nmx*cx + nmy*cy) + nmz*cz = -dot (exact);
// nd = dot'+dot' = -2*dot (exact); d2 = (sqi + sqj) + nd == fsub(s, 2dot).
__device__ __forceinline__ f2 d2pair(f2 nmx, f2 nmy, f2 nmz, f2 sqi2,
                                     float4 A, float4 B) {
#pragma clang fp contract(off)
    f2 cx = {A.x, A.y}, cy = {A.z, A.w};
    f2 cz = {B.x, B.y}, cw = {B.z, B.w};
    f2 t = nmx * cx + nmy * cy;
    f2 nd = t + nmz * cz;
    nd = nd + nd;
    f2 s = sqi2 + cw;
    return s + nd;
}

// ---------------------------------------------------------------------------
// Prep: pair-packed positions. pp4[2p]={x0,x1,y0,y1}, pp4[2p+1]={z0,z1,q0,q1}
// with q = (x*x + y*y) + z*z in exact numpy rounding.
// ---------------------------------------------------------------------------
__global__ __launch_bounds__(256) void prep_kernel(const float* __restrict__ pos,
                                                   float4* __restrict__ pp4) {
    const int p = blockIdx.x * 256 + threadIdx.x;  // pair index, < TOTAL/2
    const float* s = pos + (size_t)p * 6;
    float x0 = s[0], y0 = s[1], z0 = s[2];
    float x1 = s[3], y1 = s[4], z1 = s[5];
    float q0 = __fadd_rn(__fadd_rn(__fmul_rn(x0, x0), __fmul_rn(y0, y0)),
                         __fmul_rn(z0, z0));
    float q1 = __fadd_rn(__fadd_rn(__fmul_rn(x1, x1), __fmul_rn(y1, y1)),
                         __fmul_rn(z1, z1));
    pp4[2 * p + 0] = make_float4(x0, x1, y0, y1);
    pp4[2 * p + 1] = make_float4(z0, z1, q0, q1);
}

// ---------------------------------------------------------------------------
// kNN: block = 512 thr = 8 waves; lane = query, wave = 512-cand chunk.
// Pass1: full-chunk oct-min + med3 top-10 of oct-mins (no self-mask; self
// contributes d2 == exact 0). Merge: tau = 11th-smallest oct-min of 8-wave
// union (>= true 10th non-self d2). Pass2: packed replay, push survivors
// (d2<=tau) to per-query LDS pools. Select: exact (d2,idx) top-10, skip self.
// ---------------------------------------------------------------------------
__global__ __launch_bounds__(512, 8) void knn_kernel(const float4* __restrict__ pp4,
                                                     int* __restrict__ cnt,
                                                     int* __restrict__ colfix,
                                                     int* __restrict__ nbr) {
    __shared__ uint32_t pool[QG * PPITCH];  // 24.8 KB; pass1 lists alias first 5120 words
    __shared__ float tau_s[QG];
    __shared__ unsigned int qcnt[QG];
    float* poolf = (float*)pool;

    const int tid = threadIdx.x;
    const int lane = tid & 63;
    const int w = __builtin_amdgcn_readfirstlane(tid >> 6);
    const int batch = blockIdx.x >> 6;
    const int qloc = ((blockIdx.x & 63) << 6) | lane;
    const int gbase = batch << 12;
    const int gq = gbase + qloc;

    // my position from the pair-packed array
    float4 mA = pp4[(gq >> 1) * 2 + 0];
    float4 mB = pp4[(gq >> 1) * 2 + 1];
    const bool hi = (qloc & 1);
    const float mx = hi ? mA.y : mA.x;
    const float my = hi ? mA.w : mA.z;
    const float mz = hi ? mB.y : mB.x;
    const float sqi = hi ? mB.w : mB.z;
    const f2 nmx = {-mx, -mx}, nmy = {-my, -my}, nmz = {-mz, -mz};
    const f2 sqi2 = {sqi, sqi};

    // chunk base: float4 index of first pair of this wave's chunk
    const float4* __restrict__ cp = pp4 + (size_t)(gbase + w * CH);

    // ---- pass 1: top-10 oct-mins over the full 512-cand chunk
    float L[KK];
#pragma unroll
    for (int t = 0; t < KK; t++) L[t] = INFF;

    for (int o = 0; o < CH / 8; ++o) {  // 64 octs x 8 candidates
        const float4* cb = cp + o * 8;
        f2 d0 = d2pair(nmx, nmy, nmz, sqi2, cb[0], cb[1]);
        f2 d1 = d2pair(nmx, nmy, nmz, sqi2, cb[2], cb[3]);
        f2 d2v = d2pair(nmx, nmy, nmz, sqi2, cb[4], cb[5]);
        f2 d3 = d2pair(nmx, nmy, nmz, sqi2, cb[6], cb[7]);
        float m0 = fminf(d0.x, d0.y), m1 = fminf(d1.x, d1.y);
        float m2 = fminf(d2v.x, d2v.y), m3 = fminf(d3.x, d3.y);
        float m = fminf(fminf(m0, m1), fminf(m2, m3));
#pragma unroll
        for (int t = 0; t < KK - 1; ++t) L[t] = __builtin_amdgcn_fmed3f(L[t], L[t + 1], m);
        L[KK - 1] = fminf(L[KK - 1], m);
    }
#pragma unroll
    for (int t = 0; t < KK; t++) poolf[tid * KK + t] = L[t];
    if (tid < QG) qcnt[tid] = 0u;
    __syncthreads();

    // ---- merge: 11th-smallest oct-min of the 8-list union -> tau
    if (tid < QG) {
        int p[NW];
#pragma unroll
        for (int u = 0; u < NW; u++) p[u] = KK - 1;  // descending lists; tail = min
        float tau = INFF;
        for (int it = 0; it < KK + 1; ++it) {
            float best = INFF;
            int bw = 0;
#pragma unroll
            for (int u = 0; u < NW; u++) {
                float v = (p[u] >= 0) ? poolf[(u * QG + tid) * KK + p[u]] : INFF;
                if (v < best) { best = v; bw = u; }
            }
            p[bw]--;
            tau = best;
        }
        tau_s[tid] = tau;
    }
    __syncthreads();

    // ---- pass 2: packed replay, collect survivors (d2 <= tau; self included)
    const float tau = tau_s[lane];
    for (int pi = 0; pi < CH / 2; ++pi) {
        f2 d = d2pair(nmx, nmy, nmz, sqi2, cp[2 * pi], cp[2 * pi + 1]);
        if (fminf(d.x, d.y) <= tau) {
            if (d.x <= tau) {
                unsigned pp = atomicAdd(&qcnt[lane], 1u);
                if (pp < PCAP) {
                    pool[lane * PPITCH + 2 * pp + 0] = __float_as_uint(d.x);
                    pool[lane * PPITCH + 2 * pp + 1] = (uint32_t)(w * CH + 2 * pi);
                }
            }
            if (d.y <= tau) {
                unsigned pp = atomicAdd(&qcnt[lane], 1u);
                if (pp < PCAP) {
                    pool[lane * PPITCH + 2 * pp + 0] = __float_as_uint(d.y);
                    pool[lane * PPITCH + 2 * pp + 1] = (uint32_t)(w * CH + 2 * pi + 1);
                }
            }
        }
    }
    __syncthreads();

    // ---- select: exact (d2, idx) top-10 over survivors (skip self), write edges
    if (tid < QG) {
        uint64_t S[KK];
#pragma unroll
        for (int t = 0; t < KK; t++) S[t] = ~0ull;
        unsigned R = qcnt[tid];
        if (R > PCAP) R = PCAP;
        for (unsigned e = 0; e < R; ++e) {
            uint32_t db = pool[tid * PPITCH + 2 * e + 0];
            uint32_t ix = pool[tid * PPITCH + 2 * e + 1];
            if (ix == (uint32_t)qloc) continue;  // self (d2 == 0)
            uint64_t k64 = ((uint64_t)db << 32) | ix;
            if (k64 < S[0]) {
                bool sh[KK];
                sh[0] = true;
#pragma unroll
                for (int t = 1; t < KK; t++) sh[t] = (k64 < S[t]);
#pragma unroll
                for (int t = 0; t < KK; t++) {
                    uint64_t vac = sh[t] ? k64 : S[t];
                    S[t] = (t + 1 < KK) ? (sh[t + 1] ? S[t + 1] : vac) : vac;
                }
            }
        }
#pragma unroll
        for (int t = 0; t < KK; t++) {
            int jl = (int)(S[t] & 0xffffffffu);
            int gj = gbase + jl;
            int p = atomicAdd(&cnt[gj], 1);
            if (colfix) {
                if (p < 64) colfix[(gj << 6) | p] = gq;
            } else {
                nbr[gq * KK + t] = gj;
            }
        }
    }
}

// ---------------------------------------------------------------------------
// Bucket-path output: 4 nodes per wave, 16 lanes x float4 per node; 2-way
// unrolled gather to overlap VMEM latency.
// ---------------------------------------------------------------------------
__global__ __launch_bounds__(256) void out_bucket_kernel(const float4* __restrict__ x4,
                                                         const int* __restrict__ colfix,
                                                         const int* __restrict__ cnt,
                                                         float* __restrict__ out) {
    const int gid = blockIdx.x * 256 + threadIdx.x;
    const int n = gid >> 4;
    const int s = gid & 15;
    const int c = cnt[n];
    const int cc = (c > 64) ? 64 : c;
    const int base = n << 6;
    float4 acc = make_float4(0.f, 0.f, 0.f, 0.f);
    int e = 0;
    for (; e + 2 <= cc; e += 2) {
        int q0 = colfix[base + e], q1 = colfix[base + e + 1];
        float4 v0 = x4[(q0 << 4) | s];
        float4 v1 = x4[(q1 << 4) | s];
        acc.x += v0.x; acc.y += v0.y; acc.z += v0.z; acc.w += v0.w;
        acc.x += v1.x; acc.y += v1.y; acc.z += v1.z; acc.w += v1.w;
    }
    if (e < cc) {
        int q0 = colfix[base + e];
        float4 v0 = x4[(q0 << 4) | s];
        acc.x += v0.x; acc.y += v0.y; acc.z += v0.z; acc.w += v0.w;
    }
    const float inv = 1.0f / (float)(c > 1 ? c : 1);
    float4 mn = x4[(n << 4) | s];
    float v = fabsf(mn.x - acc.x * inv) + fabsf(mn.y - acc.y * inv) +
              fabsf(mn.z - acc.z * inv) + fabsf(mn.w - acc.w * inv);
    v += __shfl_xor(v, 1, 64);
    v += __shfl_xor(v, 2, 64);
    v += __shfl_xor(v, 4, 64);
    v += __shfl_xor(v, 8, 64);
    if (s == 0) out[n] = v;
}

// ------------------------- fallback path (small ws) -------------------------
__global__ __launch_bounds__(1024) void scan_kernel(const int* __restrict__ cnt,
                                                    int* __restrict__ offs) {
    __shared__ int lds[1024];
    const int t = threadIdx.x;
    const int base = t * 64;
    int s = 0;
    for (int i = 0; i < 64; i++) s += cnt[base + i];
    lds[t] = s;
    __syncthreads();
    for (int off = 1; off < 1024; off <<= 1) {
        int v = (t >= off) ? lds[t - off] : 0;
        __syncthreads();
        lds[t] += v;
        __syncthreads();
    }
    int run = lds[t] - s;
    for (int i = 0; i < 64; i++) {
        offs[base + i] = run;
        run += cnt[base + i];
    }
}

__global__ __launch_bounds__(256) void fill_kernel(const int* __restrict__ nbr,
                                                   int* __restrict__ offs,
                                                   int* __restrict__ col) {
    const int i = blockIdx.x * 256 + threadIdx.x;
#pragma unroll
    for (int t = 0; t < KK; t++) {
        int j = nbr[i * KK + t];
        int p = atomicAdd(&offs[j], 1);
        col[p] = i;
    }
}

__global__ __launch_bounds__(256) void out_kernel(const float* __restrict__ x,
                                                  const int* __restrict__ col,
                                                  const int* __restrict__ offs_end,
                                                  const int* __restrict__ cnt,
                                                  float* __restrict__ out) {
    const int gtid = blockIdx.x * 256 + threadIdx.x;
    const int n = gtid >> 6;
    const int lane = gtid & 63;
    const int c = cnt[n];
    const int end = offs_end[n];
    const int start = end - c;
    float s = 0.0f;
    for (int e = start; e < end; e++) {
        int i = col[e];
        s += x[(size_t)i * FD + lane];
    }
    float mean = s / (float)(c > 1 ? c : 1);
    float v = fabsf(x[(size_t)n * FD + lane] - mean);
#pragma unroll
    for (int off = 32; off; off >>= 1) v += __shfl_xor(v, off, 64);
    if (lane == 0) out[n] = v;
}

extern "C" void kernel_launch(void* const* d_in, const int* in_sizes, int n_in,
                              void* d_out, int out_size, void* d_ws, size_t ws_size,
                              hipStream_t stream) {
    const float* x = (const float*)d_in[0];
    const float* pos = (const float*)d_in[1];
    float* out = (float*)d_out;

    char* ws = (char*)d_ws;
    float4* pp4 = (float4*)(ws + 0);            // 1,048,576 B
    int* cnt = (int*)(ws + 1048576);            //   262,144 B
    // bucket path (needs 18.1 MB):
    int* colfix = (int*)(ws + 1310720);         // TOTAL*64*4 = 16,777,216 B
    // fallback path (needs 6.8 MB):
    int* nbr = (int*)(ws + 1310720);            // 2,621,440 B
    int* offs = (int*)(ws + 3932160);           //   262,144 B
    int* col = (int*)(ws + 4194304);            // 2,621,440 B

    const bool bucket = ws_size >= (size_t)(1310720 + TOTAL * 64 * 4);

    hipMemsetAsync(cnt, 0, TOTAL * sizeof(int), stream);
    hipLaunchKernelGGL(prep_kernel, dim3(TOTAL / 2 / 256), dim3(256), 0, stream, pos, pp4);
    hipLaunchKernelGGL(knn_kernel, dim3(TOTAL / QG), dim3(512), 0, stream, pp4, cnt,
                       bucket ? colfix : (int*)nullptr, bucket ? (int*)nullptr : nbr);
    if (bucket) {
        hipLaunchKernelGGL(out_bucket_kernel, dim3(TOTAL * 16 / 256), dim3(256), 0, stream,
                           (const float4*)x, colfix, cnt, out);
    } else {
        hipLaunchKernelGGL(scan_kernel, dim3(1), dim3(1024), 0, stream, cnt, offs);
        hipLaunchKernelGGL(fill_kernel, dim3(TOTAL / 256), dim3(256), 0, stream, nbr, offs, col);
        hipLaunchKernelGGL(out_kernel, dim3(TOTAL * FD / 256), dim3(256), 0, stream,
                           x, col, offs, cnt, out);
    }
}

// Round 5
// 216.654 us; speedup vs baseline: 3.5463x; 1.0401x over previous
//
#include <hip/hip_runtime.h>
#include <stdint.h>

#define NB 16
#define NN 4096
#define KK 10
#define NL 11       // pass1 list size: 11th-smallest oct-min -> tau
#define FD 64
#define TOTAL (NB * NN)
#define NW 8        // waves per knn block
#define CH 512      // candidates per wave chunk (NW*CH == NN)
#define SOCT 32     // sampled octs per chunk (first 256 cands) for pass1
#define QG 64       // queries per block (one per lane)
#define PCAP 64     // survivor pool cap per query (mean ~22, ~6 sigma margin)
#define PPITCH 129  // pool pitch in words per query

typedef float f2 __attribute__((ext_vector_type(2)));

#define INFF __int_as_float(0x7f800000)

// Packed-pair distance (pass1/pass2 MEMBERSHIP only; final keys are rescored
// with the exact scalar formula, so pk-fma contraction here cannot change
// the edge set).
__device__ __forceinline__ f2 d2pair(f2 nmx, f2 nmy, f2 nmz, f2 sqi2,
                                     float4 A, float4 B) {
#pragma clang fp contract(off)
    f2 cx = {A.x, A.y}, cy = {A.z, A.w};
    f2 cz = {B.x, B.y}, cw = {B.z, B.w};
    f2 t = nmx * cx + nmy * cy;
    f2 nd = t + nmz * cz;
    nd = nd + nd;
    f2 s = sqi2 + cw;
    return s + nd;
}

// EXACT numpy rounding - frozen since round 1 (absmax 0.75). DO NOT CHANGE.
__device__ __forceinline__ uint32_t d2exact(float mx, float my, float mz, float sqi,
                                            float cx, float cy, float cz, float cw) {
    float dot = __fadd_rn(__fadd_rn(__fmul_rn(mx, cx), __fmul_rn(my, cy)),
                          __fmul_rn(mz, cz));
    float d2 = __fsub_rn(__fadd_rn(sqi, cw), __fmul_rn(2.0f, dot));
    return __float_as_uint(d2);
}

// ---------------------------------------------------------------------------
// Prep: pair-packed positions + zero cnt (saves a memset dispatch).
// pp4[2p]={x0,x1,y0,y1}, pp4[2p+1]={z0,z1,q0,q1}, q=(x*x+y*y)+z*z numpy-exact.
// ---------------------------------------------------------------------------
__global__ __launch_bounds__(256) void prep_kernel(const float* __restrict__ pos,
                                                   float4* __restrict__ pp4,
                                                   int* __restrict__ cnt) {
    const int p = blockIdx.x * 256 + threadIdx.x;  // pair index, < TOTAL/2
    const float* s = pos + (size_t)p * 6;
    float x0 = s[0], y0 = s[1], z0 = s[2];
    float x1 = s[3], y1 = s[4], z1 = s[5];
    float q0 = __fadd_rn(__fadd_rn(__fmul_rn(x0, x0), __fmul_rn(y0, y0)),
                         __fmul_rn(z0, z0));
    float q1 = __fadd_rn(__fadd_rn(__fmul_rn(x1, x1), __fmul_rn(y1, y1)),
                         __fmul_rn(z1, z1));
    pp4[2 * p + 0] = make_float4(x0, x1, y0, y1);
    pp4[2 * p + 1] = make_float4(z0, z1, q0, q1);
    cnt[2 * p + 0] = 0;
    cnt[2 * p + 1] = 0;
}

// ---------------------------------------------------------------------------
// kNN: block = 512 thr = 8 waves; lane = query, wave = 512-cand chunk.
// Pass1: oct-min + med3 top-11 over the chunk's FIRST 256 cands (sampled).
// Merge: tau = 11th-smallest oct-min of 8-wave union (>= true 10th non-self,
// any-subset order-stat bound). Pass2: packed full-chunk replay, survivors
// (d2<=tau) to per-query LDS pools. Select: rescore survivors with the EXACT
// scalar formula, exact (d2,idx) top-10, skip self, write edges.
// ---------------------------------------------------------------------------
__global__ __launch_bounds__(512, 8) void knn_kernel(const float4* __restrict__ pp4,
                                                     int* __restrict__ cnt,
                                                     int* __restrict__ colfix,
                                                     int* __restrict__ nbr) {
    __shared__ uint32_t pool[QG * PPITCH];  // 33 KB; pass1 lists alias first 5632 words
    __shared__ float tau_s[QG];
    __shared__ unsigned int qcnt[QG];
    float* poolf = (float*)pool;

    const int tid = threadIdx.x;
    const int lane = tid & 63;
    const int w = __builtin_amdgcn_readfirstlane(tid >> 6);
    const int batch = blockIdx.x >> 6;
    const int qloc = ((blockIdx.x & 63) << 6) | lane;
    const int gbase = batch << 12;
    const int gq = gbase + qloc;

    // my position from the pair-packed array
    float4 mA = pp4[(gq >> 1) * 2 + 0];
    float4 mB = pp4[(gq >> 1) * 2 + 1];
    const bool hi = (qloc & 1);
    const float mx = hi ? mA.y : mA.x;
    const float my = hi ? mA.w : mA.z;
    const float mz = hi ? mB.y : mB.x;
    const float sqi = hi ? mB.w : mB.z;
    const f2 nmx = {-mx, -mx}, nmy = {-my, -my}, nmz = {-mz, -mz};
    const f2 sqi2 = {sqi, sqi};

    const float4* __restrict__ cp = pp4 + (size_t)(gbase + w * CH);

    // ---- pass 1: top-11 oct-mins over the sampled first 256 cands of chunk
    float L[NL];
#pragma unroll
    for (int t = 0; t < NL; t++) L[t] = INFF;

#pragma unroll 2
    for (int o = 0; o < SOCT; ++o) {  // 32 octs x 8 candidates
        const float4* cb = cp + o * 8;
        f2 d0 = d2pair(nmx, nmy, nmz, sqi2, cb[0], cb[1]);
        f2 d1 = d2pair(nmx, nmy, nmz, sqi2, cb[2], cb[3]);
        f2 d2v = d2pair(nmx, nmy, nmz, sqi2, cb[4], cb[5]);
        f2 d3 = d2pair(nmx, nmy, nmz, sqi2, cb[6], cb[7]);
        float m0 = fminf(d0.x, d0.y), m1 = fminf(d1.x, d1.y);
        float m2 = fminf(d2v.x, d2v.y), m3 = fminf(d3.x, d3.y);
        float m = fminf(fminf(m0, m1), fminf(m2, m3));
#pragma unroll
        for (int t = 0; t < NL - 1; ++t) L[t] = __builtin_amdgcn_fmed3f(L[t], L[t + 1], m);
        L[NL - 1] = fminf(L[NL - 1], m);
    }
#pragma unroll
    for (int t = 0; t < NL; t++) poolf[tid * NL + t] = L[t];
    if (tid < QG) qcnt[tid] = 0u;
    __syncthreads();

    // ---- merge: 11th-smallest oct-min of the 8-list union -> tau
    if (tid < QG) {
        int p[NW];
#pragma unroll
        for (int u = 0; u < NW; u++) p[u] = NL - 1;  // descending lists; tail = min
        float tau = INFF;
        for (int it = 0; it < NL; ++it) {
            float best = INFF;
            int bw = 0;
#pragma unroll
            for (int u = 0; u < NW; u++) {
                float v = (p[u] >= 0) ? poolf[(u * QG + tid) * NL + p[u]] : INFF;
                if (v < best) { best = v; bw = u; }
            }
            p[bw]--;
            tau = best;
        }
        tau_s[tid] = tau;
    }
    __syncthreads();

    // ---- pass 2: packed full-chunk replay, collect survivors (self included)
    const float tau = tau_s[lane];
#pragma unroll 2
    for (int pi = 0; pi < CH / 2; ++pi) {
        f2 d = d2pair(nmx, nmy, nmz, sqi2, cp[2 * pi], cp[2 * pi + 1]);
        if (fminf(d.x, d.y) <= tau) {
            if (d.x <= tau) {
                unsigned pp = atomicAdd(&qcnt[lane], 1u);
                if (pp < PCAP) pool[lane * PPITCH + 2 * pp + 1] = (uint32_t)(w * CH + 2 * pi);
            }
            if (d.y <= tau) {
                unsigned pp = atomicAdd(&qcnt[lane], 1u);
                if (pp < PCAP) pool[lane * PPITCH + 2 * pp + 1] = (uint32_t)(w * CH + 2 * pi + 1);
            }
        }
    }
    __syncthreads();

    // ---- select: rescore survivors EXACTLY, (d2,idx) top-10, skip self
    if (tid < QG) {
        uint64_t S[KK];
#pragma unroll
        for (int t = 0; t < KK; t++) S[t] = ~0ull;
        unsigned R = qcnt[tid];
        if (R > PCAP) R = PCAP;
        for (unsigned e = 0; e < R; ++e) {
            uint32_t ix = pool[tid * PPITCH + 2 * e + 1];
            if (ix == (uint32_t)qloc) continue;  // self
            int g = gbase + (int)ix;
            float4 A = pp4[(g >> 1) * 2 + 0];
            float4 B = pp4[(g >> 1) * 2 + 1];
            bool ch = (ix & 1);
            uint32_t db = d2exact(mx, my, mz, sqi,
                                  ch ? A.y : A.x, ch ? A.w : A.z,
                                  ch ? B.y : B.x, ch ? B.w : B.z);
            uint64_t k64 = ((uint64_t)db << 32) | ix;
            if (k64 < S[0]) {
                bool sh[KK];
                sh[0] = true;
#pragma unroll
                for (int t = 1; t < KK; t++) sh[t] = (k64 < S[t]);
#pragma unroll
                for (int t = 0; t < KK; t++) {
                    uint64_t vac = sh[t] ? k64 : S[t];
                    S[t] = (t + 1 < KK) ? (sh[t + 1] ? S[t + 1] : vac) : vac;
                }
            }
        }
#pragma unroll
        for (int t = 0; t < KK; t++) {
            int jl = (int)(S[t] & 0xffffffffu);
            int gj = gbase + jl;
            int p = atomicAdd(&cnt[gj], 1);
            if (colfix) {
                if (p < 64) colfix[(gj << 6) | p] = gq;
            } else {
                nbr[gq * KK + t] = gj;
            }
        }
    }
}

// ---------------------------------------------------------------------------
// Bucket-path output: 4 nodes per wave, 16 lanes x float4 per node; 2-way
// unrolled gather to overlap VMEM latency.
// ---------------------------------------------------------------------------
__global__ __launch_bounds__(256) void out_bucket_kernel(const float4* __restrict__ x4,
                                                         const int* __restrict__ colfix,
                                                         const int* __restrict__ cnt,
                                                         float* __restrict__ out) {
    const int gid = blockIdx.x * 256 + threadIdx.x;
    const int n = gid >> 4;
    const int s = gid & 15;
    const int c = cnt[n];
    const int cc = (c > 64) ? 64 : c;
    const int base = n << 6;
    float4 acc = make_float4(0.f, 0.f, 0.f, 0.f);
    int e = 0;
    for (; e + 2 <= cc; e += 2) {
        int q0 = colfix[base + e], q1 = colfix[base + e + 1];
        float4 v0 = x4[(q0 << 4) | s];
        float4 v1 = x4[(q1 << 4) | s];
        acc.x += v0.x; acc.y += v0.y; acc.z += v0.z; acc.w += v0.w;
        acc.x += v1.x; acc.y += v1.y; acc.z += v1.z; acc.w += v1.w;
    }
    if (e < cc) {
        int q0 = colfix[base + e];
        float4 v0 = x4[(q0 << 4) | s];
        acc.x += v0.x; acc.y += v0.y; acc.z += v0.z; acc.w += v0.w;
    }
    const float inv = 1.0f / (float)(c > 1 ? c : 1);
    float4 mn = x4[(n << 4) | s];
    float v = fabsf(mn.x - acc.x * inv) + fabsf(mn.y - acc.y * inv) +
              fabsf(mn.z - acc.z * inv) + fabsf(mn.w - acc.w * inv);
    v += __shfl_xor(v, 1, 64);
    v += __shfl_xor(v, 2, 64);
    v += __shfl_xor(v, 4, 64);
    v += __shfl_xor(v, 8, 64);
    if (s == 0) out[n] = v;
}

// ------------------------- fallback path (small ws) -------------------------
__global__ __launch_bounds__(1024) void scan_kernel(const int* __restrict__ cnt,
                                                    int* __restrict__ offs) {
    __shared__ int lds[1024];
    const int t = threadIdx.x;
    const int base = t * 64;
    int s = 0;
    for (int i = 0; i < 64; i++) s += cnt[base + i];
    lds[t] = s;
    __syncthreads();
    for (int off = 1; off < 1024; off <<= 1) {
        int v = (t >= off) ? lds[t - off] : 0;
        __syncthreads();
        lds[t] += v;
        __syncthreads();
    }
    int run = lds[t] - s;
    for (int i = 0; i < 64; i++) {
        offs[base + i] = run;
        run += cnt[base + i];
    }
}

__global__ __launch_bounds__(256) void fill_kernel(const int* __restrict__ nbr,
                                                   int* __restrict__ offs,
                                                   int* __restrict__ col) {
    const int i = blockIdx.x * 256 + threadIdx.x;
#pragma unroll
    for (int t = 0; t < KK; t++) {
        int j = nbr[i * KK + t];
        int p = atomicAdd(&offs[j], 1);
        col[p] = i;
    }
}

__global__ __launch_bounds__(256) void out_kernel(const float* __restrict__ x,
                                                  const int* __restrict__ col,
                                                  const int* __restrict__ offs_end,
                                                  const int* __restrict__ cnt,
                                                  float* __restrict__ out) {
    const int gtid = blockIdx.x * 256 + threadIdx.x;
    const int n = gtid >> 6;
    const int lane = gtid & 63;
    const int c = cnt[n];
    const int end = offs_end[n];
    const int start = end - c;
    float s = 0.0f;
    for (int e = start; e < end; e++) {
        int i = col[e];
        s += x[(size_t)i * FD + lane];
    }
    float mean = s / (float)(c > 1 ? c : 1);
    float v = fabsf(x[(size_t)n * FD + lane] - mean);
#pragma unroll
    for (int off = 32; off; off >>= 1) v += __shfl_xor(v, off, 64);
    if (lane == 0) out[n] = v;
}

extern "C" void kernel_launch(void* const* d_in, const int* in_sizes, int n_in,
                              void* d_out, int out_size, void* d_ws, size_t ws_size,
                              hipStream_t stream) {
    const float* x = (const float*)d_in[0];
    const float* pos = (const float*)d_in[1];
    float* out = (float*)d_out;

    char* ws = (char*)d_ws;
    float4* pp4 = (float4*)(ws + 0);            // 1,048,576 B
    int* cnt = (int*)(ws + 1048576);            //   262,144 B
    // bucket path (needs 18.1 MB):
    int* colfix = (int*)(ws + 1310720);         // TOTAL*64*4 = 16,777,216 B
    // fallback path (needs 6.8 MB):
    int* nbr = (int*)(ws + 1310720);            // 2,621,440 B
    int* offs = (int*)(ws + 3932160);           //   262,144 B
    int* col = (int*)(ws + 4194304);            // 2,621,440 B

    const bool bucket = ws_size >= (size_t)(1310720 + TOTAL * 64 * 4);

    hipLaunchKernelGGL(prep_kernel, dim3(TOTAL / 2 / 256), dim3(256), 0, stream, pos, pp4, cnt);
    hipLaunchKernelGGL(knn_kernel, dim3(TOTAL / QG), dim3(512), 0, stream, pp4, cnt,
                       bucket ? colfix : (int*)nullptr, bucket ? (int*)nullptr : nbr);
    if (bucket) {
        hipLaunchKernelGGL(out_bucket_kernel, dim3(TOTAL * 16 / 256), dim3(256), 0, stream,
                           (const float4*)x, colfix, cnt, out);
    } else {
        hipLaunchKernelGGL(scan_kernel, dim3(1), dim3(1024), 0, stream, cnt, offs);
        hipLaunchKernelGGL(fill_kernel, dim3(TOTAL / 256), dim3(256), 0, stream, nbr, offs, col);
        hipLaunchKernelGGL(out_kernel, dim3(TOTAL * FD / 256), dim3(256), 0, stream,
                           x, col, offs, cnt, out);
    }
}

// Round 6
// 202.362 us; speedup vs baseline: 3.7968x; 1.0706x over previous
//
#include <hip/hip_runtime.h>
#include <stdint.h>

#define NB 16
#define NN 4096
#define KK 10
#define NL 11       // pass1 list size: 11th-smallest oct-min -> tau
#define FD 64
#define TOTAL (NB * NN)
#define NW 8        // waves per knn block
#define CH 512      // candidates per wave chunk (NW*CH == NN)
#define SOCT 32     // sampled octs per chunk (first 256 cands) for pass1
#define QG 64       // queries per block (one per lane)
#define WCAP 24     // survivor cap per (query,wave) cell (mean 2.75, ~1e-13 tail)
#define WPITCH 25   // cell pitch in halfwords (breaks same-bank stride)

#define INFF __int_as_float(0x7f800000)

// Membership formula (pass1 + pass2, IDENTICAL inlined code -> identical bits).
// Candidate coords (cx,cy,cz,cq) are wave-uniform -> expected in SGPRs; each
// fma reads exactly one SGPR operand. vx2=-2mx etc. are per-lane VGPRs.
__device__ __forceinline__ float Fd2(float cx, float cy, float cz, float cq,
                                     float vx2, float vy2, float vz2, float sqi) {
    return __fmaf_rn(vz2, cz, __fmaf_rn(vy2, cy, __fmaf_rn(vx2, cx, __fadd_rn(sqi, cq))));
}

// EXACT numpy rounding - frozen since round 1 (absmax 0.75). DO NOT CHANGE.
__device__ __forceinline__ uint32_t d2exact(float mx, float my, float mz, float sqi,
                                            float cx, float cy, float cz, float cw) {
    float dot = __fadd_rn(__fadd_rn(__fmul_rn(mx, cx), __fmul_rn(my, cy)),
                          __fmul_rn(mz, cz));
    float d2 = __fsub_rn(__fadd_rn(sqi, cw), __fmul_rn(2.0f, dot));
    return __float_as_uint(d2);
}

// ---------------------------------------------------------------------------
// Prep: pair-packed positions + zero cnt.
// pp4[2p]={x0,x1,y0,y1}, pp4[2p+1]={z0,z1,q0,q1}, q=(x*x+y*y)+z*z numpy-exact.
// ---------------------------------------------------------------------------
__global__ __launch_bounds__(256) void prep_kernel(const float* __restrict__ pos,
                                                   float4* __restrict__ pp4,
                                                   int* __restrict__ cnt) {
    const int p = blockIdx.x * 256 + threadIdx.x;  // pair index, < TOTAL/2
    const float* s = pos + (size_t)p * 6;
    float x0 = s[0], y0 = s[1], z0 = s[2];
    float x1 = s[3], y1 = s[4], z1 = s[5];
    float q0 = __fadd_rn(__fadd_rn(__fmul_rn(x0, x0), __fmul_rn(y0, y0)),
                         __fmul_rn(z0, z0));
    float q1 = __fadd_rn(__fadd_rn(__fmul_rn(x1, x1), __fmul_rn(y1, y1)),
                         __fmul_rn(z1, z1));
    pp4[2 * p + 0] = make_float4(x0, x1, y0, y1);
    pp4[2 * p + 1] = make_float4(z0, z1, q0, q1);
    cnt[2 * p + 0] = 0;
    cnt[2 * p + 1] = 0;
}

// ---------------------------------------------------------------------------
// kNN: block = 512 thr = 8 waves; lane = query, wave = 512-cand chunk.
// Candidate data is wave-uniform (scalar loads); distance = 4 VALU w/ SGPR
// operand. Pass1: top-11 oct-mins over first 256 cands. Merge: tau = 11th
// smallest of 8-wave octmin union (*1.00001 guard). Pass2: full-chunk replay,
// survivors to private per-(query,wave) u16 LDS cells (no atomics). Select:
// exact-rescore survivors, (d2,idx) top-10, skip self, write edges.
// ---------------------------------------------------------------------------
__global__ __launch_bounds__(512, 8) void knn_kernel(const float4* __restrict__ pp4,
                                                     int* __restrict__ cnt,
                                                     int* __restrict__ colfix,
                                                     int* __restrict__ nbr) {
    __shared__ uint32_t smem[6400];      // pass1 lists (5632 w) then u16 pools (6400 w)
    __shared__ float tau_s[QG];
    __shared__ uint32_t qcntw[QG * NW];
    float* listf = (float*)smem;
    uint16_t* pool16 = (uint16_t*)smem;

    const int tid = threadIdx.x;
    const int lane = tid & 63;
    const int w = __builtin_amdgcn_readfirstlane(tid >> 6);
    const int batch = blockIdx.x >> 6;
    const int qloc = ((blockIdx.x & 63) << 6) | lane;  // batch-local query idx
    const int gbase = batch << 12;
    const int gq = gbase + qloc;

    // my query position (from pair-packed array)
    float4 mA = pp4[(gq >> 1) * 2 + 0];
    float4 mB = pp4[(gq >> 1) * 2 + 1];
    const bool hi = (qloc & 1);
    const float mx = hi ? mA.y : mA.x;
    const float my = hi ? mA.w : mA.z;
    const float mz = hi ? mB.y : mB.x;
    const float sqi = hi ? mB.w : mB.z;
    const float vx2 = __fmul_rn(-2.0f, mx);
    const float vy2 = __fmul_rn(-2.0f, my);
    const float vz2 = __fmul_rn(-2.0f, mz);

    // chunk base in float4s (pair j>>1 -> float4s 2*(j>>1)); gbase+w*CH even
    const float4* __restrict__ cp = pp4 + (size_t)(gbase + w * CH);

#define D8(cb)                                                        \
    float4 A0 = (cb)[0], B0 = (cb)[1], A1 = (cb)[2], B1 = (cb)[3];    \
    float4 A2 = (cb)[4], B2 = (cb)[5], A3 = (cb)[6], B3 = (cb)[7];    \
    float d0 = Fd2(A0.x, A0.z, B0.x, B0.z, vx2, vy2, vz2, sqi);       \
    float d1 = Fd2(A0.y, A0.w, B0.y, B0.w, vx2, vy2, vz2, sqi);       \
    float d2 = Fd2(A1.x, A1.z, B1.x, B1.z, vx2, vy2, vz2, sqi);       \
    float d3 = Fd2(A1.y, A1.w, B1.y, B1.w, vx2, vy2, vz2, sqi);       \
    float d4 = Fd2(A2.x, A2.z, B2.x, B2.z, vx2, vy2, vz2, sqi);       \
    float d5 = Fd2(A2.y, A2.w, B2.y, B2.w, vx2, vy2, vz2, sqi);       \
    float d6 = Fd2(A3.x, A3.z, B3.x, B3.z, vx2, vy2, vz2, sqi);       \
    float d7 = Fd2(A3.y, A3.w, B3.y, B3.w, vx2, vy2, vz2, sqi);

    // ---- pass 1: top-11 oct-mins over sampled first 256 cands of chunk
    float L[NL];
#pragma unroll
    for (int t = 0; t < NL; t++) L[t] = INFF;

#pragma unroll 2
    for (int o = 0; o < SOCT; ++o) {
        const float4* cb = cp + o * 8;
        D8(cb);
        float m = fminf(fminf(fminf(d0, d1), fminf(d2, d3)),
                        fminf(fminf(d4, d5), fminf(d6, d7)));
#pragma unroll
        for (int t = 0; t < NL - 1; ++t) L[t] = __builtin_amdgcn_fmed3f(L[t], L[t + 1], m);
        L[NL - 1] = fminf(L[NL - 1], m);
    }
#pragma unroll
    for (int t = 0; t < NL; t++) listf[tid * NL + t] = L[t];
    __syncthreads();

    // ---- merge: 11th-smallest oct-min of the 8-list union -> tau
    if (tid < QG) {
        int p[NW];
#pragma unroll
        for (int u = 0; u < NW; u++) p[u] = NL - 1;  // descending lists; tail = min
        float tau = INFF;
        for (int it = 0; it < NL; ++it) {
            float best = INFF;
            int bw = 0;
#pragma unroll
            for (int u = 0; u < NW; u++) {
                float v = (p[u] >= 0) ? listf[((u << 6) | tid) * NL + p[u]] : INFF;
                if (v < best) { best = v; bw = u; }
            }
            p[bw]--;
            tau = best;
        }
        tau_s[tid] = tau;
    }
    __syncthreads();  // merge reads done; pool16 may now overwrite list region

    // ---- pass 2: full-chunk replay into private (query,wave) u16 cell
    const float tau = tau_s[lane] * 1.00001f;  // guard (exact rescore fixes all)
    const uint32_t cell0 = (uint32_t)((lane * NW + w) * WPITCH);  // halfword idx
    uint32_t cpos = cell0;
    for (int o = 0; o < CH / 8; ++o) {
        const float4* cb = cp + o * 8;
        D8(cb);
        const uint32_t jb = (uint32_t)(w * CH + o * 8);
#define PUSH(dv, off)                                              \
        if ((dv) <= tau && cpos < cell0 + WCAP) {                  \
            pool16[cpos] = (uint16_t)(jb + (off));                 \
            cpos++;                                                \
        }
        PUSH(d0, 0) PUSH(d1, 1) PUSH(d2, 2) PUSH(d3, 3)
        PUSH(d4, 4) PUSH(d5, 5) PUSH(d6, 6) PUSH(d7, 7)
#undef PUSH
    }
    qcntw[lane * NW + w] = cpos - cell0;
    __syncthreads();

    // ---- select: exact rescore of survivors, (d2,idx) top-10, skip self
    if (tid < QG) {
        uint64_t S[KK];
#pragma unroll
        for (int t = 0; t < KK; t++) S[t] = ~0ull;
#pragma unroll
        for (int u = 0; u < NW; u++) {
            uint32_t c2 = qcntw[tid * NW + u];
            const uint16_t* st = pool16 + (tid * NW + u) * WPITCH;
            for (uint32_t e = 0; e < c2; ++e) {
                uint32_t ix = st[e];
                if (ix == (uint32_t)qloc) continue;  // self
                int g = gbase + (int)ix;
                float4 A = pp4[(g >> 1) * 2 + 0];
                float4 B = pp4[(g >> 1) * 2 + 1];
                bool ch = (ix & 1);
                uint32_t db = d2exact(mx, my, mz, sqi,
                                      ch ? A.y : A.x, ch ? A.w : A.z,
                                      ch ? B.y : B.x, ch ? B.w : B.z);
                uint64_t k64 = ((uint64_t)db << 32) | ix;
                if (k64 < S[0]) {
                    bool sh[KK];
                    sh[0] = true;
#pragma unroll
                    for (int t = 1; t < KK; t++) sh[t] = (k64 < S[t]);
#pragma unroll
                    for (int t = 0; t < KK; t++) {
                        uint64_t vac = sh[t] ? k64 : S[t];
                        S[t] = (t + 1 < KK) ? (sh[t + 1] ? S[t + 1] : vac) : vac;
                    }
                }
            }
        }
#pragma unroll
        for (int t = 0; t < KK; t++) {
            int jl = (int)(S[t] & 0xffffffffu);
            int gj = gbase + jl;
            int p = atomicAdd(&cnt[gj], 1);
            if (colfix) {
                if (p < 64) colfix[(gj << 6) | p] = gq;
            } else {
                nbr[gq * KK + t] = gj;
            }
        }
    }
#undef D8
}

// ---------------------------------------------------------------------------
// Bucket-path output: 4 nodes per wave, 16 lanes x float4 per node; 2-way
// unrolled gather to overlap VMEM latency.
// ---------------------------------------------------------------------------
__global__ __launch_bounds__(256) void out_bucket_kernel(const float4* __restrict__ x4,
                                                         const int* __restrict__ colfix,
                                                         const int* __restrict__ cnt,
                                                         float* __restrict__ out) {
    const int gid = blockIdx.x * 256 + threadIdx.x;
    const int n = gid >> 4;
    const int s = gid & 15;
    const int c = cnt[n];
    const int cc = (c > 64) ? 64 : c;
    const int base = n << 6;
    float4 acc = make_float4(0.f, 0.f, 0.f, 0.f);
    int e = 0;
    for (; e + 2 <= cc; e += 2) {
        int q0 = colfix[base + e], q1 = colfix[base + e + 1];
        float4 v0 = x4[(q0 << 4) | s];
        float4 v1 = x4[(q1 << 4) | s];
        acc.x += v0.x; acc.y += v0.y; acc.z += v0.z; acc.w += v0.w;
        acc.x += v1.x; acc.y += v1.y; acc.z += v1.z; acc.w += v1.w;
    }
    if (e < cc) {
        int q0 = colfix[base + e];
        float4 v0 = x4[(q0 << 4) | s];
        acc.x += v0.x; acc.y += v0.y; acc.z += v0.z; acc.w += v0.w;
    }
    const float inv = 1.0f / (float)(c > 1 ? c : 1);
    float4 mn = x4[(n << 4) | s];
    float v = fabsf(mn.x - acc.x * inv) + fabsf(mn.y - acc.y * inv) +
              fabsf(mn.z - acc.z * inv) + fabsf(mn.w - acc.w * inv);
    v += __shfl_xor(v, 1, 64);
    v += __shfl_xor(v, 2, 64);
    v += __shfl_xor(v, 4, 64);
    v += __shfl_xor(v, 8, 64);
    if (s == 0) out[n] = v;
}

// ------------------------- fallback path (small ws) -------------------------
__global__ __launch_bounds__(1024) void scan_kernel(const int* __restrict__ cnt,
                                                    int* __restrict__ offs) {
    __shared__ int lds[1024];
    const int t = threadIdx.x;
    const int base = t * 64;
    int s = 0;
    for (int i = 0; i < 64; i++) s += cnt[base + i];
    lds[t] = s;
    __syncthreads();
    for (int off = 1; off < 1024; off <<= 1) {
        int v = (t >= off) ? lds[t - off] : 0;
        __syncthreads();
        lds[t] += v;
        __syncthreads();
    }
    int run = lds[t] - s;
    for (int i = 0; i < 64; i++) {
        offs[base + i] = run;
        run += cnt[base + i];
    }
}

__global__ __launch_bounds__(256) void fill_kernel(const int* __restrict__ nbr,
                                                   int* __restrict__ offs,
                                                   int* __restrict__ col) {
    const int i = blockIdx.x * 256 + threadIdx.x;
#pragma unroll
    for (int t = 0; t < KK; t++) {
        int j = nbr[i * KK + t];
        int p = atomicAdd(&offs[j], 1);
        col[p] = i;
    }
}

__global__ __launch_bounds__(256) void out_kernel(const float* __restrict__ x,
                                                  const int* __restrict__ col,
                                                  const int* __restrict__ offs_end,
                                                  const int* __restrict__ cnt,
                                                  float* __restrict__ out) {
    const int gtid = blockIdx.x * 256 + threadIdx.x;
    const int n = gtid >> 6;
    const int lane = gtid & 63;
    const int c = cnt[n];
    const int end = offs_end[n];
    const int start = end - c;
    float s = 0.0f;
    for (int e = start; e < end; e++) {
        int i = col[e];
        s += x[(size_t)i * FD + lane];
    }
    float mean = s / (float)(c > 1 ? c : 1);
    float v = fabsf(x[(size_t)n * FD + lane] - mean);
#pragma unroll
    for (int off = 32; off; off >>= 1) v += __shfl_xor(v, off, 64);
    if (lane == 0) out[n] = v;
}

extern "C" void kernel_launch(void* const* d_in, const int* in_sizes, int n_in,
                              void* d_out, int out_size, void* d_ws, size_t ws_size,
                              hipStream_t stream) {
    const float* x = (const float*)d_in[0];
    const float* pos = (const float*)d_in[1];
    float* out = (float*)d_out;

    char* ws = (char*)d_ws;
    float4* pp4 = (float4*)(ws + 0);            // 1,048,576 B
    int* cnt = (int*)(ws + 1048576);            //   262,144 B
    // bucket path (needs 18.1 MB):
    int* colfix = (int*)(ws + 1310720);         // TOTAL*64*4 = 16,777,216 B
    // fallback path (needs 6.8 MB):
    int* nbr = (int*)(ws + 1310720);            // 2,621,440 B
    int* offs = (int*)(ws + 3932160);           //   262,144 B
    int* col = (int*)(ws + 4194304);            // 2,621,440 B

    const bool bucket = ws_size >= (size_t)(1310720 + TOTAL * 64 * 4);

    hipLaunchKernelGGL(prep_kernel, dim3(TOTAL / 2 / 256), dim3(256), 0, stream, pos, pp4, cnt);
    hipLaunchKernelGGL(knn_kernel, dim3(TOTAL / QG), dim3(512), 0, stream, pp4, cnt,
                       bucket ? colfix : (int*)nullptr, bucket ? (int*)nullptr : nbr);
    if (bucket) {
        hipLaunchKernelGGL(out_bucket_kernel, dim3(TOTAL * 16 / 256), dim3(256), 0, stream,
                           (const float4*)x, colfix, cnt, out);
    } else {
        hipLaunchKernelGGL(scan_kernel, dim3(1), dim3(1024), 0, stream, cnt, offs);
        hipLaunchKernelGGL(fill_kernel, dim3(TOTAL / 256), dim3(256), 0, stream, nbr, offs, col);
        hipLaunchKernelGGL(out_kernel, dim3(TOTAL * FD / 256), dim3(256), 0, stream,
                           x, col, offs, cnt, out);
    }
}

// Round 7
// 190.709 us; speedup vs baseline: 4.0288x; 1.0611x over previous
//
#include <hip/hip_runtime.h>
#include <stdint.h>

#define NB 16
#define NN 4096
#define KK 10
#define NL 11       // pass1 list size: 11th-smallest oct-min -> tau
#define FD 64
#define TOTAL (NB * NN)
#define NW 8        // waves per knn block
#define CH 512      // candidates per wave chunk (NW*CH == NN)
#define SOCT 32     // sampled octs per chunk (first 256 cands) for pass1
#define QG 64       // queries per block (one per lane)
#define WCAP 24     // survivor cap per (query,wave) cell (mean ~2.8, huge margin)
#define WPITCH 25   // cell pitch in halfwords

#define INFF __int_as_float(0x7f800000)

typedef float f2 __attribute__((ext_vector_type(2)));

// Packed membership distance: candidate coords are wave-uniform f2 (SGPR
// pairs); vx2/vy2/vz2/sqi are per-lane splats. Lowers to v_pk_fma_f32 with
// one SGPR-pair operand. MEMBERSHIP ONLY - final keys use d2exact.
__device__ __forceinline__ f2 FdP(f2 cx, f2 cy, f2 cz, f2 cq,
                                  f2 vx2, f2 vy2, f2 vz2, f2 sqi2) {
#pragma clang fp contract(fast)
    f2 t = sqi2 + cq;
    t = vx2 * cx + t;
    t = vy2 * cy + t;
    t = vz2 * cz + t;
    return t;
}

// EXACT numpy rounding - frozen since round 1 (absmax 0.75). DO NOT CHANGE.
__device__ __forceinline__ uint32_t d2exact(float mx, float my, float mz, float sqi,
                                            float cx, float cy, float cz, float cw) {
    float dot = __fadd_rn(__fadd_rn(__fmul_rn(mx, cx), __fmul_rn(my, cy)),
                          __fmul_rn(mz, cz));
    float d2 = __fsub_rn(__fadd_rn(sqi, cw), __fmul_rn(2.0f, dot));
    return __float_as_uint(d2);
}

// ---------------------------------------------------------------------------
// Prep: pair-packed positions + zero cnt.
// pp4[2p]={x0,x1,y0,y1}, pp4[2p+1]={z0,z1,q0,q1}, q=(x*x+y*y)+z*z numpy-exact.
// ---------------------------------------------------------------------------
__global__ __launch_bounds__(256) void prep_kernel(const float* __restrict__ pos,
                                                   float4* __restrict__ pp4,
                                                   int* __restrict__ cnt) {
    const int p = blockIdx.x * 256 + threadIdx.x;  // pair index, < TOTAL/2
    const float* s = pos + (size_t)p * 6;
    float x0 = s[0], y0 = s[1], z0 = s[2];
    float x1 = s[3], y1 = s[4], z1 = s[5];
    float q0 = __fadd_rn(__fadd_rn(__fmul_rn(x0, x0), __fmul_rn(y0, y0)),
                         __fmul_rn(z0, z0));
    float q1 = __fadd_rn(__fadd_rn(__fmul_rn(x1, x1), __fmul_rn(y1, y1)),
                         __fmul_rn(z1, z1));
    pp4[2 * p + 0] = make_float4(x0, x1, y0, y1);
    pp4[2 * p + 1] = make_float4(z0, z1, q0, q1);
    cnt[2 * p + 0] = 0;
    cnt[2 * p + 1] = 0;
}

// ---------------------------------------------------------------------------
// kNN: block = 512 thr = 8 waves; lane = query, wave = 512-cand chunk.
// Candidate data wave-uniform (scalar loads as f2); distance = v_pk_fma (2
// slots/cand). Pass1: top-11 oct-mins over first 256 cands. Merge: tau =
// 11th-smallest octmin of 8-wave union (+guard). Pass2: packed full-chunk
// replay with any-of-8 push guard into private (query,wave) u16 LDS cells.
// Select: exact-rescore survivors, (d2,idx) top-10, skip self, write edges.
// Batch = blockIdx&15 -> XCD L2 affinity for the 1MB/batch pp4 slice.
// ---------------------------------------------------------------------------
__global__ __launch_bounds__(512, 8) void knn_kernel(const float4* __restrict__ pp4,
                                                     int* __restrict__ cnt,
                                                     int* __restrict__ colfix,
                                                     int* __restrict__ nbr) {
    __shared__ uint32_t smem[6400];      // pass1 lists (5632 w) then u16 pools (6400 w)
    __shared__ float tau_s[QG];
    __shared__ uint32_t qcntw[QG * NW];
    float* listf = (float*)smem;
    uint16_t* pool16 = (uint16_t*)smem;

    const int tid = threadIdx.x;
    const int lane = tid & 63;
    const int w = __builtin_amdgcn_readfirstlane(tid >> 6);
    const int batch = blockIdx.x & 15;                  // XCD-affinity swizzle
    const int qloc = ((blockIdx.x >> 4) << 6) | lane;   // batch-local query idx
    const int gbase = batch << 12;
    const int gq = gbase + qloc;

    // my query position (from pair-packed array)
    float4 mA = pp4[(gq >> 1) * 2 + 0];
    float4 mB = pp4[(gq >> 1) * 2 + 1];
    const bool hi = (qloc & 1);
    const float mx = hi ? mA.y : mA.x;
    const float my = hi ? mA.w : mA.z;
    const float mz = hi ? mB.y : mB.x;
    const float sqi = hi ? mB.w : mB.z;
    const f2 vx22 = {__fmul_rn(-2.0f, mx), __fmul_rn(-2.0f, mx)};
    const f2 vy22 = {__fmul_rn(-2.0f, my), __fmul_rn(-2.0f, my)};
    const f2 vz22 = {__fmul_rn(-2.0f, mz), __fmul_rn(-2.0f, mz)};
    const f2 sqi22 = {sqi, sqi};

    // chunk base as f2: pair p -> f2s {x01,y01,z01,q01} at 4p..4p+3
    const f2* __restrict__ cp2 = (const f2*)(pp4 + (size_t)(gbase + w * CH));

#define D8P(cb2)                                                      \
    f2 X0 = (cb2)[0],  Y0 = (cb2)[1],  Z0 = (cb2)[2],  Q0 = (cb2)[3]; \
    f2 X1 = (cb2)[4],  Y1 = (cb2)[5],  Z1 = (cb2)[6],  Q1 = (cb2)[7]; \
    f2 X2 = (cb2)[8],  Y2 = (cb2)[9],  Z2 = (cb2)[10], Q2 = (cb2)[11];\
    f2 X3 = (cb2)[12], Y3 = (cb2)[13], Z3 = (cb2)[14], Q3 = (cb2)[15];\
    f2 e0 = FdP(X0, Y0, Z0, Q0, vx22, vy22, vz22, sqi22);             \
    f2 e1 = FdP(X1, Y1, Z1, Q1, vx22, vy22, vz22, sqi22);             \
    f2 e2 = FdP(X2, Y2, Z2, Q2, vx22, vy22, vz22, sqi22);             \
    f2 e3 = FdP(X3, Y3, Z3, Q3, vx22, vy22, vz22, sqi22);

    // ---- pass 1: top-11 oct-mins over sampled first 256 cands of chunk
    float L[NL];
#pragma unroll
    for (int t = 0; t < NL; t++) L[t] = INFF;

#pragma unroll 2
    for (int o = 0; o < SOCT; ++o) {
        const f2* cb2 = cp2 + o * 16;
        D8P(cb2);
        float m = fminf(fminf(fminf(e0.x, e0.y), fminf(e1.x, e1.y)),
                        fminf(fminf(e2.x, e2.y), fminf(e3.x, e3.y)));
#pragma unroll
        for (int t = 0; t < NL - 1; ++t) L[t] = __builtin_amdgcn_fmed3f(L[t], L[t + 1], m);
        L[NL - 1] = fminf(L[NL - 1], m);
    }
#pragma unroll
    for (int t = 0; t < NL; t++) listf[tid * NL + t] = L[t];
    __syncthreads();

    // ---- merge: 11th-smallest oct-min of the 8-list union -> tau
    if (tid < QG) {
        int p[NW];
#pragma unroll
        for (int u = 0; u < NW; u++) p[u] = NL - 1;  // descending lists; tail = min
        float tau = INFF;
        for (int it = 0; it < NL; ++it) {
            float best = INFF;
            int bw = 0;
#pragma unroll
            for (int u = 0; u < NW; u++) {
                float v = (p[u] >= 0) ? listf[((u << 6) | tid) * NL + p[u]] : INFF;
                if (v < best) { best = v; bw = u; }
            }
            p[bw]--;
            tau = best;
        }
        tau_s[tid] = tau;
    }
    __syncthreads();  // merge reads done; pool16 may now overwrite list region

    // ---- pass 2: packed full-chunk replay into private (query,wave) u16 cell
    // guard: covers |packed - exact| rigorously (order-stat bound + 2*eps)
    const float tau = tau_s[lane] * 1.0001f + 1e-5f;
    const uint32_t cell0 = (uint32_t)((lane * NW + w) * WPITCH);  // halfword idx
    uint32_t cpos = cell0;
#pragma unroll 2
    for (int o = 0; o < CH / 8; ++o) {
        const f2* cb2 = cp2 + o * 16;
        D8P(cb2);
        const uint32_t jb = (uint32_t)(w * CH + o * 8);
        bool h0 = e0.x <= tau, h1 = e0.y <= tau, h2 = e1.x <= tau, h3 = e1.y <= tau;
        bool h4 = e2.x <= tau, h5 = e2.y <= tau, h6 = e3.x <= tau, h7 = e3.y <= tau;
        if (h0 | h1 | h2 | h3 | h4 | h5 | h6 | h7) {
#define PUSH(hv, off)                                              \
            if ((hv) && cpos < cell0 + WCAP) {                     \
                pool16[cpos] = (uint16_t)(jb + (off));             \
                cpos++;                                            \
            }
            PUSH(h0, 0) PUSH(h1, 1) PUSH(h2, 2) PUSH(h3, 3)
            PUSH(h4, 4) PUSH(h5, 5) PUSH(h6, 6) PUSH(h7, 7)
#undef PUSH
        }
    }
    qcntw[lane * NW + w] = cpos - cell0;
    __syncthreads();

    // ---- select: exact rescore of survivors, (d2,idx) top-10, skip self
    if (tid < QG) {
        uint64_t S[KK];
#pragma unroll
        for (int t = 0; t < KK; t++) S[t] = ~0ull;
#pragma unroll
        for (int u = 0; u < NW; u++) {
            uint32_t c2 = qcntw[tid * NW + u];
            const uint16_t* st = pool16 + (tid * NW + u) * WPITCH;
            for (uint32_t e = 0; e < c2; ++e) {
                uint32_t ix = st[e];
                if (ix == (uint32_t)qloc) continue;  // self
                int g = gbase + (int)ix;
                float4 A = pp4[(g >> 1) * 2 + 0];
                float4 B = pp4[(g >> 1) * 2 + 1];
                bool ch = (ix & 1);
                uint32_t db = d2exact(mx, my, mz, sqi,
                                      ch ? A.y : A.x, ch ? A.w : A.z,
                                      ch ? B.y : B.x, ch ? B.w : B.z);
                uint64_t k64 = ((uint64_t)db << 32) | ix;
                if (k64 < S[0]) {
                    bool sh[KK];
                    sh[0] = true;
#pragma unroll
                    for (int t = 1; t < KK; t++) sh[t] = (k64 < S[t]);
#pragma unroll
                    for (int t = 0; t < KK; t++) {
                        uint64_t vac = sh[t] ? k64 : S[t];
                        S[t] = (t + 1 < KK) ? (sh[t + 1] ? S[t + 1] : vac) : vac;
                    }
                }
            }
        }
#pragma unroll
        for (int t = 0; t < KK; t++) {
            int jl = (int)(S[t] & 0xffffffffu);
            int gj = gbase + jl;
            int p = atomicAdd(&cnt[gj], 1);
            if (colfix) {
                if (p < 64) colfix[(gj << 6) | p] = gq;
            } else {
                nbr[gq * KK + t] = gj;
            }
        }
    }
#undef D8P
}

// ---------------------------------------------------------------------------
// Bucket-path output: 4 nodes per wave, 16 lanes x float4 per node.
// int4 colfix loads (4 edge indices per dwordx4), 4 gathers in flight.
// Batch = blockIdx&15 -> XCD L2 affinity for the 1MB/batch x slice.
// ---------------------------------------------------------------------------
__global__ __launch_bounds__(256) void out_bucket_kernel(const float4* __restrict__ x4,
                                                         const int* __restrict__ colfix,
                                                         const int* __restrict__ cnt,
                                                         float* __restrict__ out) {
    const int b = blockIdx.x;
    const int g = b & 15;                 // batch
    const int i = b >> 4;                 // block-within-batch, 0..255
    const int n = (g << 12) | (i << 4) | (threadIdx.x >> 4);
    const int s = threadIdx.x & 15;
    const int c = cnt[n];
    const int cc = (c > 64) ? 64 : c;
    const int4* cf4 = (const int4*)(colfix + ((size_t)n << 6));
    float4 acc = make_float4(0.f, 0.f, 0.f, 0.f);
    for (int eb = 0; eb < cc; eb += 4) {
        int4 Q = cf4[eb >> 2];
        float4 v0 = x4[((size_t)Q.x << 4) | s];
        acc.x += v0.x; acc.y += v0.y; acc.z += v0.z; acc.w += v0.w;
        if (eb + 1 < cc) {
            float4 v1 = x4[((size_t)Q.y << 4) | s];
            acc.x += v1.x; acc.y += v1.y; acc.z += v1.z; acc.w += v1.w;
        }
        if (eb + 2 < cc) {
            float4 v2 = x4[((size_t)Q.z << 4) | s];
            acc.x += v2.x; acc.y += v2.y; acc.z += v2.z; acc.w += v2.w;
        }
        if (eb + 3 < cc) {
            float4 v3 = x4[((size_t)Q.w << 4) | s];
            acc.x += v3.x; acc.y += v3.y; acc.z += v3.z; acc.w += v3.w;
        }
    }
    const float inv = 1.0f / (float)(c > 1 ? c : 1);
    float4 mn = x4[((size_t)n << 4) | s];
    float v = fabsf(mn.x - acc.x * inv) + fabsf(mn.y - acc.y * inv) +
              fabsf(mn.z - acc.z * inv) + fabsf(mn.w - acc.w * inv);
    v += __shfl_xor(v, 1, 64);
    v += __shfl_xor(v, 2, 64);
    v += __shfl_xor(v, 4, 64);
    v += __shfl_xor(v, 8, 64);
    if (s == 0) out[n] = v;
}

// ------------------------- fallback path (small ws) -------------------------
__global__ __launch_bounds__(1024) void scan_kernel(const int* __restrict__ cnt,
                                                    int* __restrict__ offs) {
    __shared__ int lds[1024];
    const int t = threadIdx.x;
    const int base = t * 64;
    int s = 0;
    for (int i = 0; i < 64; i++) s += cnt[base + i];
    lds[t] = s;
    __syncthreads();
    for (int off = 1; off < 1024; off <<= 1) {
        int v = (t >= off) ? lds[t - off] : 0;
        __syncthreads();
        lds[t] += v;
        __syncthreads();
    }
    int run = lds[t] - s;
    for (int i = 0; i < 64; i++) {
        offs[base + i] = run;
        run += cnt[base + i];
    }
}

__global__ __launch_bounds__(256) void fill_kernel(const int* __restrict__ nbr,
                                                   int* __restrict__ offs,
                                                   int* __restrict__ col) {
    const int i = blockIdx.x * 256 + threadIdx.x;
#pragma unroll
    for (int t = 0; t < KK; t++) {
        int j = nbr[i * KK + t];
        int p = atomicAdd(&offs[j], 1);
        col[p] = i;
    }
}

__global__ __launch_bounds__(256) void out_kernel(const float* __restrict__ x,
                                                  const int* __restrict__ col,
                                                  const int* __restrict__ offs_end,
                                                  const int* __restrict__ cnt,
                                                  float* __restrict__ out) {
    const int gtid = blockIdx.x * 256 + threadIdx.x;
    const int n = gtid >> 6;
    const int lane = gtid & 63;
    const int c = cnt[n];
    const int end = offs_end[n];
    const int start = end - c;
    float s = 0.0f;
    for (int e = start; e < end; e++) {
        int i = col[e];
        s += x[(size_t)i * FD + lane];
    }
    float mean = s / (float)(c > 1 ? c : 1);
    float v = fabsf(x[(size_t)n * FD + lane] - mean);
#pragma unroll
    for (int off = 32; off; off >>= 1) v += __shfl_xor(v, off, 64);
    if (lane == 0) out[n] = v;
}

extern "C" void kernel_launch(void* const* d_in, const int* in_sizes, int n_in,
                              void* d_out, int out_size, void* d_ws, size_t ws_size,
                              hipStream_t stream) {
    const float* x = (const float*)d_in[0];
    const float* pos = (const float*)d_in[1];
    float* out = (float*)d_out;

    char* ws = (char*)d_ws;
    float4* pp4 = (float4*)(ws + 0);            // 1,048,576 B
    int* cnt = (int*)(ws + 1048576);            //   262,144 B
    // bucket path (needs 18.1 MB):
    int* colfix = (int*)(ws + 1310720);         // TOTAL*64*4 = 16,777,216 B
    // fallback path (needs 6.8 MB):
    int* nbr = (int*)(ws + 1310720);            // 2,621,440 B
    int* offs = (int*)(ws + 3932160);           //   262,144 B
    int* col = (int*)(ws + 4194304);            // 2,621,440 B

    const bool bucket = ws_size >= (size_t)(1310720 + TOTAL * 64 * 4);

    hipLaunchKernelGGL(prep_kernel, dim3(TOTAL / 2 / 256), dim3(256), 0, stream, pos, pp4, cnt);
    hipLaunchKernelGGL(knn_kernel, dim3(TOTAL / QG), dim3(512), 0, stream, pp4, cnt,
                       bucket ? colfix : (int*)nullptr, bucket ? (int*)nullptr : nbr);
    if (bucket) {
        hipLaunchKernelGGL(out_bucket_kernel, dim3(TOTAL * 16 / 256), dim3(256), 0, stream,
                           (const float4*)x, colfix, cnt, out);
    } else {
        hipLaunchKernelGGL(scan_kernel, dim3(1), dim3(1024), 0, stream, cnt, offs);
        hipLaunchKernelGGL(fill_kernel, dim3(TOTAL / 256), dim3(256), 0, stream, nbr, offs, col);
        hipLaunchKernelGGL(out_kernel, dim3(TOTAL * FD / 256), dim3(256), 0, stream,
                           x, col, offs, cnt, out);
    }
}